// Round 4
// baseline (231.403 us; speedup 1.0000x reference)
//
#include <hip/hip_runtime.h>

// pred: [T=2048, B=64, C=512] f32, mask: [T*B, 1] f32.
// loss = -sum_{p>0.9} p / max(cnt,1), 0 if cnt==0.
// Only the per-row argmax can exceed 0.9 (softmax sums to 1), so per row:
//   m = max(x), s = sum exp(x-m), pmax = 1/s; selected iff pmax > 0.9.
//
// Single fused kernel (split-k fixup pattern): each block stores a
// (total,cnt) partial, takes a device-scope ticket; the unique block that
// sees old%NBLOCKS == NBLOCKS-1 (unique for ANY ticket start value since
// NBLOCKS | 2^32 — robust to 0xAA poison / leftover state) reduces all
// partials with agent-scope loads and writes the loss.

#define NCLS 512
#define THRESH 0.9f
#define NBLOCKS 2048

// native clang vector: __builtin_nontemporal_load requires scalar/vector type,
// not HIP's struct-based float4
typedef float f32x4 __attribute__((ext_vector_type(4)));

__device__ __forceinline__ void row_reduce(f32x4 a, f32x4 b, float mval,
                                           float& wTotal, float& wCnt) {
    float x0 = a.x * mval, x1 = a.y * mval, x2 = a.z * mval, x3 = a.w * mval;
    float x4 = b.x * mval, x5 = b.y * mval, x6 = b.z * mval, x7 = b.w * mval;

    float mx = fmaxf(fmaxf(fmaxf(x0, x1), fmaxf(x2, x3)),
                     fmaxf(fmaxf(x4, x5), fmaxf(x6, x7)));
    #pragma unroll
    for (int off = 1; off < 64; off <<= 1)
        mx = fmaxf(mx, __shfl_xor(mx, off));

    float s = __expf(x0 - mx) + __expf(x1 - mx) + __expf(x2 - mx) + __expf(x3 - mx)
            + __expf(x4 - mx) + __expf(x5 - mx) + __expf(x6 - mx) + __expf(x7 - mx);
    #pragma unroll
    for (int off = 1; off < 64; off <<= 1)
        s += __shfl_xor(s, off);

    float pmax = 1.0f / s;          // prob of the argmax element
    if (pmax > THRESH) { wTotal += pmax; wCnt += 1.0f; }
}

__global__ __launch_bounds__(256) void pl_fused(const float* __restrict__ pred,
                                                const float* __restrict__ mask,
                                                float2* __restrict__ partial,
                                                unsigned int* __restrict__ ticket,
                                                float* __restrict__ out,
                                                int N) {
    const int lane = threadIdx.x & 63;
    const int wid  = threadIdx.x >> 6;   // 4 waves per block

    float wTotal = 0.0f;
    float wCnt   = 0.0f;

    const long long rstride = (long long)gridDim.x * 4;
    long long row = (long long)blockIdx.x * 4 + wid;

    // unroll x2: two rows' loads (4x 16B/lane) in flight before either
    // row's dependent shuffle/exp chain starts. Non-temporal: pure stream.
    for (; row + rstride < (long long)N; row += 2 * rstride) {
        const long long r2 = row + rstride;
        const float m1 = mask[row];
        const float m2 = mask[r2];
        const f32x4* rp1 = (const f32x4*)(pred + row * NCLS);
        const f32x4* rp2 = (const f32x4*)(pred + r2 * NCLS);
        f32x4 a1 = __builtin_nontemporal_load(rp1 + lane);
        f32x4 b1 = __builtin_nontemporal_load(rp1 + lane + 64);
        f32x4 a2 = __builtin_nontemporal_load(rp2 + lane);
        f32x4 b2 = __builtin_nontemporal_load(rp2 + lane + 64);
        row_reduce(a1, b1, m1, wTotal, wCnt);
        row_reduce(a2, b2, m2, wTotal, wCnt);
    }
    for (; row < (long long)N; row += rstride) {
        const float m1 = mask[row];
        const f32x4* rp1 = (const f32x4*)(pred + row * NCLS);
        f32x4 a1 = __builtin_nontemporal_load(rp1 + lane);
        f32x4 b1 = __builtin_nontemporal_load(rp1 + lane + 64);
        row_reduce(a1, b1, m1, wTotal, wCnt);
    }

    __shared__ float sT[4];
    __shared__ float sC[4];
    __shared__ int sLast;
    if (lane == 0) { sT[wid] = wTotal; sC[wid] = wCnt; }
    __syncthreads();
    if (threadIdx.x == 0) {
        float t = sT[0] + sT[1] + sT[2] + sT[3];
        float c = sC[0] + sC[1] + sC[2] + sC[3];
        partial[blockIdx.x] = make_float2(t, c);
        __threadfence();   // make partial visible device-wide before ticket
        unsigned int old = __hip_atomic_fetch_add(ticket, 1u, __ATOMIC_ACQ_REL,
                                                  __HIP_MEMORY_SCOPE_AGENT);
        sLast = ((old & (NBLOCKS - 1)) == (NBLOCKS - 1)) ? 1 : 0;
    }
    __syncthreads();

    if (sLast) {
        // last-arriving block: all 2048 partials are visible (acq_rel ticket)
        float t = 0.0f, c = 0.0f;
        for (int i = threadIdx.x; i < NBLOCKS; i += 256) {
            // agent-scope loads: bypass stale per-XCD caches
            float px = __hip_atomic_load(&partial[i].x, __ATOMIC_RELAXED,
                                         __HIP_MEMORY_SCOPE_AGENT);
            float py = __hip_atomic_load(&partial[i].y, __ATOMIC_RELAXED,
                                         __HIP_MEMORY_SCOPE_AGENT);
            t += px;
            c += py;
        }
        #pragma unroll
        for (int off = 1; off < 64; off <<= 1) {
            t += __shfl_xor(t, off);
            c += __shfl_xor(c, off);
        }
        __shared__ float fT[4];
        __shared__ float fC[4];
        if (lane == 0) { fT[wid] = t; fC[wid] = c; }
        __syncthreads();
        if (threadIdx.x == 0) {
            float tt = fT[0] + fT[1] + fT[2] + fT[3];
            float cc = fC[0] + fC[1] + fC[2] + fC[3];
            out[0] = (cc > 0.0f) ? (-tt / cc) : 0.0f;
        }
    }
}

extern "C" void kernel_launch(void* const* d_in, const int* in_sizes, int n_in,
                              void* d_out, int out_size, void* d_ws, size_t ws_size,
                              hipStream_t stream) {
    const float* pred = (const float*)d_in[0];
    const float* mask = (const float*)d_in[1];
    float* out = (float*)d_out;
    float2* partial = (float2*)d_ws;
    unsigned int* ticket = (unsigned int*)((char*)d_ws + NBLOCKS * sizeof(float2));

    const int N = in_sizes[0] / NCLS;    // number of rows (T*B)

    pl_fused<<<NBLOCKS, 256, 0, stream>>>(pred, mask, partial, ticket, out, N);
}

// Round 5
// 174.587 us; speedup vs baseline: 1.3254x; 1.3254x over previous
//
#include <hip/hip_runtime.h>

// pred: [T=2048, B=64, C=512] f32, mask: [T*B, 1] f32.
// loss = -sum_{p>0.9} p / max(cnt,1), 0 if cnt==0.
// Only the per-row argmax can exceed 0.9 (softmax sums to 1), so per row:
//   m = max(x), s = sum exp(x-m), pmax = 1/s; selected iff pmax > 0.9.
//
// Single fused kernel (split-k fixup pattern): each block stores a
// (total,cnt) partial, takes a device-scope ticket; the unique block that
// sees old%NBLOCKS == NBLOCKS-1 (unique for ANY ticket start value since
// NBLOCKS | 2^32 — robust to 0xAA poison / leftover state) reduces all
// partials with agent-scope loads and writes the loss.
//
// NOTE (R4 lesson): __builtin_nontemporal_load on gfx950 bypasses the
// L2/TCC fast path — streaming BW collapsed 5.9 TB/s -> 0.58 TB/s.
// Plain cached float4 loads ARE the fast path.

#define NCLS 512
#define THRESH 0.9f
#define NBLOCKS 2048

typedef float f32x4 __attribute__((ext_vector_type(4)));

__device__ __forceinline__ void row_reduce(f32x4 a, f32x4 b, float mval,
                                           float& wTotal, float& wCnt) {
    float x0 = a.x * mval, x1 = a.y * mval, x2 = a.z * mval, x3 = a.w * mval;
    float x4 = b.x * mval, x5 = b.y * mval, x6 = b.z * mval, x7 = b.w * mval;

    float mx = fmaxf(fmaxf(fmaxf(x0, x1), fmaxf(x2, x3)),
                     fmaxf(fmaxf(x4, x5), fmaxf(x6, x7)));
    #pragma unroll
    for (int off = 1; off < 64; off <<= 1)
        mx = fmaxf(mx, __shfl_xor(mx, off));

    float s = __expf(x0 - mx) + __expf(x1 - mx) + __expf(x2 - mx) + __expf(x3 - mx)
            + __expf(x4 - mx) + __expf(x5 - mx) + __expf(x6 - mx) + __expf(x7 - mx);
    #pragma unroll
    for (int off = 1; off < 64; off <<= 1)
        s += __shfl_xor(s, off);

    float pmax = 1.0f / s;          // prob of the argmax element
    if (pmax > THRESH) { wTotal += pmax; wCnt += 1.0f; }
}

__global__ __launch_bounds__(256) void pl_fused(const float* __restrict__ pred,
                                                const float* __restrict__ mask,
                                                float2* __restrict__ partial,
                                                unsigned int* __restrict__ ticket,
                                                float* __restrict__ out,
                                                int N) {
    const int lane = threadIdx.x & 63;
    const int wid  = threadIdx.x >> 6;   // 4 waves per block

    float wTotal = 0.0f;
    float wCnt   = 0.0f;

    const long long rstride = (long long)gridDim.x * 4;
    long long row = (long long)blockIdx.x * 4 + wid;

    // unroll x2: two rows' loads (4x 16B/lane) in flight before either
    // row's dependent shuffle/exp chain starts.
    for (; row + rstride < (long long)N; row += 2 * rstride) {
        const long long r2 = row + rstride;
        const float m1 = mask[row];
        const float m2 = mask[r2];
        const f32x4* rp1 = (const f32x4*)(pred + row * NCLS);
        const f32x4* rp2 = (const f32x4*)(pred + r2 * NCLS);
        f32x4 a1 = rp1[lane];
        f32x4 b1 = rp1[lane + 64];
        f32x4 a2 = rp2[lane];
        f32x4 b2 = rp2[lane + 64];
        row_reduce(a1, b1, m1, wTotal, wCnt);
        row_reduce(a2, b2, m2, wTotal, wCnt);
    }
    for (; row < (long long)N; row += rstride) {
        const float m1 = mask[row];
        const f32x4* rp1 = (const f32x4*)(pred + row * NCLS);
        f32x4 a1 = rp1[lane];
        f32x4 b1 = rp1[lane + 64];
        row_reduce(a1, b1, m1, wTotal, wCnt);
    }

    __shared__ float sT[4];
    __shared__ float sC[4];
    __shared__ int sLast;
    if (lane == 0) { sT[wid] = wTotal; sC[wid] = wCnt; }
    __syncthreads();
    if (threadIdx.x == 0) {
        float t = sT[0] + sT[1] + sT[2] + sT[3];
        float c = sC[0] + sC[1] + sC[2] + sC[3];
        partial[blockIdx.x] = make_float2(t, c);
        __threadfence();   // make partial visible device-wide before ticket
        unsigned int old = __hip_atomic_fetch_add(ticket, 1u, __ATOMIC_ACQ_REL,
                                                  __HIP_MEMORY_SCOPE_AGENT);
        sLast = ((old & (NBLOCKS - 1)) == (NBLOCKS - 1)) ? 1 : 0;
    }
    __syncthreads();

    if (sLast) {
        // last-arriving block: all 2048 partials are visible (acq_rel ticket)
        float t = 0.0f, c = 0.0f;
        for (int i = threadIdx.x; i < NBLOCKS; i += 256) {
            // agent-scope loads: bypass stale per-XCD caches
            float px = __hip_atomic_load(&partial[i].x, __ATOMIC_RELAXED,
                                         __HIP_MEMORY_SCOPE_AGENT);
            float py = __hip_atomic_load(&partial[i].y, __ATOMIC_RELAXED,
                                         __HIP_MEMORY_SCOPE_AGENT);
            t += px;
            c += py;
        }
        #pragma unroll
        for (int off = 1; off < 64; off <<= 1) {
            t += __shfl_xor(t, off);
            c += __shfl_xor(c, off);
        }
        __shared__ float fT[4];
        __shared__ float fC[4];
        if (lane == 0) { fT[wid] = t; fC[wid] = c; }
        __syncthreads();
        if (threadIdx.x == 0) {
            float tt = fT[0] + fT[1] + fT[2] + fT[3];
            float cc = fC[0] + fC[1] + fC[2] + fC[3];
            out[0] = (cc > 0.0f) ? (-tt / cc) : 0.0f;
        }
    }
}

extern "C" void kernel_launch(void* const* d_in, const int* in_sizes, int n_in,
                              void* d_out, int out_size, void* d_ws, size_t ws_size,
                              hipStream_t stream) {
    const float* pred = (const float*)d_in[0];
    const float* mask = (const float*)d_in[1];
    float* out = (float*)d_out;
    float2* partial = (float2*)d_ws;
    unsigned int* ticket = (unsigned int*)((char*)d_ws + NBLOCKS * sizeof(float2));

    const int N = in_sizes[0] / NCLS;    // number of rows (T*B)

    pl_fused<<<NBLOCKS, 256, 0, stream>>>(pred, mask, partial, ticket, out, N);
}

// Round 6
// 52.945 us; speedup vs baseline: 4.3706x; 3.2975x over previous
//
#include <hip/hip_runtime.h>

// pred: [T=2048, B=64, C=512] f32, mask: [T*B, 1] f32.
// loss = -sum_{p>0.9} p / max(cnt,1), 0 if cnt==0.
// Only the per-row argmax can exceed 0.9 (softmax sums to 1), so per row:
//   m = max(x), s = sum exp(x-m), pmax = 1/s; selected iff pmax > 0.9.
//
// Single fused kernel. R5 lesson: per-block acq_rel/threadfence publish costs
// ~140ns*2048 serialized (L2 writeback+inv per block, cross-XCD) = +125..245us.
// Instead: ALL cross-block traffic via the coherence point with RELAXED ops —
//   - partials: agent-scope relaxed atomic STORES (bypass L2, idempotent per
//     replay -> deterministic across graph replays, no reset needed)
//   - completion: raw s_waitcnt vmcnt(0) (store acks) before the ticket
//   - ticket: agent-scope RELAXED fetch_add; block seeing old%2048==2047 is
//     unique for any start value (2048 consecutive ints cover all residues)
//   - reducer: agent-scope relaxed atomic loads (read coherence point)
// No fences, no L2 flushes anywhere.

#define NCLS 512
#define THRESH 0.9f
#define NBLOCKS 2048

typedef float f32x4 __attribute__((ext_vector_type(4)));

__device__ __forceinline__ void row_reduce(f32x4 a, f32x4 b, float mval,
                                           float& wTotal, float& wCnt) {
    float x0 = a.x * mval, x1 = a.y * mval, x2 = a.z * mval, x3 = a.w * mval;
    float x4 = b.x * mval, x5 = b.y * mval, x6 = b.z * mval, x7 = b.w * mval;

    float mx = fmaxf(fmaxf(fmaxf(x0, x1), fmaxf(x2, x3)),
                     fmaxf(fmaxf(x4, x5), fmaxf(x6, x7)));
    #pragma unroll
    for (int off = 1; off < 64; off <<= 1)
        mx = fmaxf(mx, __shfl_xor(mx, off));

    float s = __expf(x0 - mx) + __expf(x1 - mx) + __expf(x2 - mx) + __expf(x3 - mx)
            + __expf(x4 - mx) + __expf(x5 - mx) + __expf(x6 - mx) + __expf(x7 - mx);
    #pragma unroll
    for (int off = 1; off < 64; off <<= 1)
        s += __shfl_xor(s, off);

    float pmax = 1.0f / s;          // prob of the argmax element
    if (pmax > THRESH) { wTotal += pmax; wCnt += 1.0f; }
}

__global__ __launch_bounds__(256) void pl_fused(const float* __restrict__ pred,
                                                const float* __restrict__ mask,
                                                float* __restrict__ pT,
                                                float* __restrict__ pC,
                                                unsigned int* __restrict__ ticket,
                                                float* __restrict__ out,
                                                int N) {
    const int lane = threadIdx.x & 63;
    const int wid  = threadIdx.x >> 6;   // 4 waves per block

    float wTotal = 0.0f;
    float wCnt   = 0.0f;

    const long long rstride = (long long)gridDim.x * 4;
    long long row = (long long)blockIdx.x * 4 + wid;

    // unroll x2: two rows' loads (4x 16B/lane) in flight before either
    // row's dependent shuffle/exp chain starts. Plain cached loads (R4
    // lesson: nontemporal loads are a slow path on gfx950).
    for (; row + rstride < (long long)N; row += 2 * rstride) {
        const long long r2 = row + rstride;
        const float m1 = mask[row];
        const float m2 = mask[r2];
        const f32x4* rp1 = (const f32x4*)(pred + row * NCLS);
        const f32x4* rp2 = (const f32x4*)(pred + r2 * NCLS);
        f32x4 a1 = rp1[lane];
        f32x4 b1 = rp1[lane + 64];
        f32x4 a2 = rp2[lane];
        f32x4 b2 = rp2[lane + 64];
        row_reduce(a1, b1, m1, wTotal, wCnt);
        row_reduce(a2, b2, m2, wTotal, wCnt);
    }
    for (; row < (long long)N; row += rstride) {
        const float m1 = mask[row];
        const f32x4* rp1 = (const f32x4*)(pred + row * NCLS);
        f32x4 a1 = rp1[lane];
        f32x4 b1 = rp1[lane + 64];
        row_reduce(a1, b1, m1, wTotal, wCnt);
    }

    __shared__ float sT[4];
    __shared__ float sC[4];
    __shared__ int sLast;
    if (lane == 0) { sT[wid] = wTotal; sC[wid] = wCnt; }
    __syncthreads();
    if (threadIdx.x == 0) {
        float t = sT[0] + sT[1] + sT[2] + sT[3];
        float c = sC[0] + sC[1] + sC[2] + sC[3];
        // publish partials at the coherence point (no L2 involvement)
        __hip_atomic_store(&pT[blockIdx.x], t, __ATOMIC_RELAXED,
                           __HIP_MEMORY_SCOPE_AGENT);
        __hip_atomic_store(&pC[blockIdx.x], c, __ATOMIC_RELAXED,
                           __HIP_MEMORY_SCOPE_AGENT);
        // wait for the store acks — partials are globally visible now
        asm volatile("s_waitcnt vmcnt(0)" ::: "memory");
        unsigned int old = __hip_atomic_fetch_add(ticket, 1u, __ATOMIC_RELAXED,
                                                  __HIP_MEMORY_SCOPE_AGENT);
        sLast = ((old & (NBLOCKS - 1)) == (NBLOCKS - 1)) ? 1 : 0;
    }
    __syncthreads();

    if (sLast) {
        // unique last-arriving block: every other block's partials completed
        // (vmcnt(0)) before its ticket RMW, and ticket RMWs are totally
        // ordered at the coherence point.
        float t = 0.0f, c = 0.0f;
        for (int i = threadIdx.x; i < NBLOCKS; i += 256) {
            t += __hip_atomic_load(&pT[i], __ATOMIC_RELAXED,
                                   __HIP_MEMORY_SCOPE_AGENT);
            c += __hip_atomic_load(&pC[i], __ATOMIC_RELAXED,
                                   __HIP_MEMORY_SCOPE_AGENT);
        }
        #pragma unroll
        for (int off = 1; off < 64; off <<= 1) {
            t += __shfl_xor(t, off);
            c += __shfl_xor(c, off);
        }
        __shared__ float fT[4];
        __shared__ float fC[4];
        if (lane == 0) { fT[wid] = t; fC[wid] = c; }
        __syncthreads();
        if (threadIdx.x == 0) {
            float tt = fT[0] + fT[1] + fT[2] + fT[3];
            float cc = fC[0] + fC[1] + fC[2] + fC[3];
            out[0] = (cc > 0.0f) ? (-tt / cc) : 0.0f;
        }
    }
}

extern "C" void kernel_launch(void* const* d_in, const int* in_sizes, int n_in,
                              void* d_out, int out_size, void* d_ws, size_t ws_size,
                              hipStream_t stream) {
    const float* pred = (const float*)d_in[0];
    const float* mask = (const float*)d_in[1];
    float* out = (float*)d_out;
    float* pT = (float*)d_ws;
    float* pC = pT + NBLOCKS;
    unsigned int* ticket = (unsigned int*)(pC + NBLOCKS);

    const int N = in_sizes[0] / NCLS;    // number of rows (T*B)

    pl_fused<<<NBLOCKS, 256, 0, stream>>>(pred, mask, pT, pC, ticket, out, N);
}

// Round 7
// 49.727 us; speedup vs baseline: 4.6535x; 1.0647x over previous
//
#include <hip/hip_runtime.h>

// pred: [T=2048, B=64, C=512] f32, mask: [T*B, 1] f32.
// loss = -sum_{p>0.9} p / max(cnt,1), 0 if cnt==0.
// Only the per-row argmax can exceed 0.9 (softmax sums to 1), so per row:
//   m = max(x), s = sum exp(x-m), pmax = 1/s; selected iff pmax > 0.9.
//
// Two-kernel structure (R6 lesson: fused single-kernel epilogue costs more
// than the second launch — 2048 uncached agent-scope loads + ticket tail
// ≈ +5us vs ~2us for a tiny second dispatch).
// Main kernel: contiguous row partition — each wave owns 16 consecutive
// rows (32KB linear stream) instead of grid-striding 16MB apart, for DRAM
// row-buffer locality. Partials via plain stores (no init needed).
// R4/R5 lessons kept: no nontemporal loads (slow path on gfx950); no
// acq_rel/threadfence publish (L2 flush per block, serialized).

#define NCLS 512
#define THRESH 0.9f
#define NBLOCKS 2048
#define WAVES_PER_BLOCK 4

typedef float f32x4 __attribute__((ext_vector_type(4)));

__device__ __forceinline__ void row_reduce(f32x4 a, f32x4 b, float mval,
                                           float& wTotal, float& wCnt) {
    float x0 = a.x * mval, x1 = a.y * mval, x2 = a.z * mval, x3 = a.w * mval;
    float x4 = b.x * mval, x5 = b.y * mval, x6 = b.z * mval, x7 = b.w * mval;

    float mx = fmaxf(fmaxf(fmaxf(x0, x1), fmaxf(x2, x3)),
                     fmaxf(fmaxf(x4, x5), fmaxf(x6, x7)));
    #pragma unroll
    for (int off = 1; off < 64; off <<= 1)
        mx = fmaxf(mx, __shfl_xor(mx, off));

    float s = __expf(x0 - mx) + __expf(x1 - mx) + __expf(x2 - mx) + __expf(x3 - mx)
            + __expf(x4 - mx) + __expf(x5 - mx) + __expf(x6 - mx) + __expf(x7 - mx);
    #pragma unroll
    for (int off = 1; off < 64; off <<= 1)
        s += __shfl_xor(s, off);

    float pmax = 1.0f / s;          // prob of the argmax element
    if (pmax > THRESH) { wTotal += pmax; wCnt += 1.0f; }
}

__global__ __launch_bounds__(256) void pl_main(const float* __restrict__ pred,
                                               const float* __restrict__ mask,
                                               float2* __restrict__ partial,
                                               int N) {
    const int lane = threadIdx.x & 63;
    const int wid  = threadIdx.x >> 6;

    const long long nwaves = (long long)gridDim.x * WAVES_PER_BLOCK;
    const long long wave   = (long long)blockIdx.x * WAVES_PER_BLOCK + wid;
    const long long rpw    = N / nwaves;          // rows per wave (16 here)
    const long long base   = wave * rpw;
    const long long end    = base + rpw;

    float wTotal = 0.0f;
    float wCnt   = 0.0f;

    // contiguous 32KB stream per wave; unroll x2 keeps 4 loads in flight
    long long row = base;
    for (; row + 1 < end; row += 2) {
        const float m1 = mask[row];
        const float m2 = mask[row + 1];
        const f32x4* rp1 = (const f32x4*)(pred + row * NCLS);
        const f32x4* rp2 = (const f32x4*)(pred + (row + 1) * NCLS);
        f32x4 a1 = rp1[lane];
        f32x4 b1 = rp1[lane + 64];
        f32x4 a2 = rp2[lane];
        f32x4 b2 = rp2[lane + 64];
        row_reduce(a1, b1, m1, wTotal, wCnt);
        row_reduce(a2, b2, m2, wTotal, wCnt);
    }
    for (; row < end; ++row) {
        const float m1 = mask[row];
        const f32x4* rp1 = (const f32x4*)(pred + row * NCLS);
        f32x4 a1 = rp1[lane];
        f32x4 b1 = rp1[lane + 64];
        row_reduce(a1, b1, m1, wTotal, wCnt);
    }
    // global tail (rows not covered when N % nwaves != 0): one row per wave
    {
        long long tail = nwaves * rpw + wave;
        if (tail < (long long)N) {
            const float m1 = mask[tail];
            const f32x4* rp1 = (const f32x4*)(pred + tail * NCLS);
            f32x4 a1 = rp1[lane];
            f32x4 b1 = rp1[lane + 64];
            row_reduce(a1, b1, m1, wTotal, wCnt);
        }
    }

    __shared__ float sT[WAVES_PER_BLOCK];
    __shared__ float sC[WAVES_PER_BLOCK];
    if (lane == 0) { sT[wid] = wTotal; sC[wid] = wCnt; }
    __syncthreads();
    if (threadIdx.x == 0) {
        float t = 0.0f, c = 0.0f;
        #pragma unroll
        for (int i = 0; i < WAVES_PER_BLOCK; ++i) { t += sT[i]; c += sC[i]; }
        partial[blockIdx.x] = make_float2(t, c);
    }
}

__global__ __launch_bounds__(256) void pl_final(const float2* __restrict__ partial,
                                                int nb, float* __restrict__ out) {
    const int lane = threadIdx.x & 63;
    const int wid  = threadIdx.x >> 6;

    float t = 0.0f, c = 0.0f;
    for (int i = threadIdx.x; i < nb; i += 256) {
        float2 p = partial[i];
        t += p.x;
        c += p.y;
    }
    #pragma unroll
    for (int off = 1; off < 64; off <<= 1) {
        t += __shfl_xor(t, off);
        c += __shfl_xor(c, off);
    }
    __shared__ float sT[4];
    __shared__ float sC[4];
    if (lane == 0) { sT[wid] = t; sC[wid] = c; }
    __syncthreads();
    if (threadIdx.x == 0) {
        float tt = sT[0] + sT[1] + sT[2] + sT[3];
        float cc = sC[0] + sC[1] + sC[2] + sC[3];
        out[0] = (cc > 0.0f) ? (-tt / cc) : 0.0f;
    }
}

extern "C" void kernel_launch(void* const* d_in, const int* in_sizes, int n_in,
                              void* d_out, int out_size, void* d_ws, size_t ws_size,
                              hipStream_t stream) {
    const float* pred = (const float*)d_in[0];
    const float* mask = (const float*)d_in[1];
    float* out = (float*)d_out;
    float2* partial = (float2*)d_ws;

    const int N = in_sizes[0] / NCLS;    // number of rows (T*B)

    pl_main<<<NBLOCKS, 256, 0, stream>>>(pred, mask, partial, N);
    pl_final<<<1, 256, 0, stream>>>(partial, NBLOCKS, out);
}